// Round 8
// baseline (37.127 us; speedup 1.0000x reference)
//
#include <hip/hip_runtime.h>
#include <math.h>

#define BB 4
#define NN 512
#define PP 2048
#define EE 32768
#define FH 128
#define DRBF 32
#define INDIM 416
#define CUT 4.0f
#define PI_F 3.14159265358979323846f
#define NMAX 8192
#define HP 424            // padded hS row (floats)
#define NE 4              // edges per block iteration

struct __align__(16) Rec { float dx, dy, dz; unsigned int ap; };

// Pass 1: compact survivors; also zero the output accumulator.
__global__ __launch_bounds__(256) void filter_kernel(
    const int* __restrict__ pe, const float* __restrict__ pdisp,
    const float* __restrict__ cell, const float* __restrict__ atom_xyz,
    const float* __restrict__ probe_xyz, int* __restrict__ cnt,
    Rec* __restrict__ recs, float* __restrict__ out) {
  int e = blockIdx.x * blockDim.x + threadIdx.x;   // grid covers exactly B*E
  if (e < BB * PP) out[e] = 0.0f;
  int b = e >> 15;
  int2 ap = ((const int2*)pe)[e];
  float pd0 = pdisp[e*3], pd1 = pdisp[e*3+1], pd2 = pdisp[e*3+2];
  const float* cb = cell + b*9;
  float d0 = pd0*cb[0] + pd1*cb[3] + pd2*cb[6];
  float d1 = pd0*cb[1] + pd1*cb[4] + pd2*cb[7];
  float d2 = pd0*cb[2] + pd1*cb[5] + pd2*cb[8];
  int ag = b*NN + ap.x;
  int pg = b*PP + ap.y;
  float dx = probe_xyz[pg*3]   - (atom_xyz[ag*3]   + d0);
  float dy = probe_xyz[pg*3+1] - (atom_xyz[ag*3+1] + d1);
  float dz = probe_xyz[pg*3+2] - (atom_xyz[ag*3+2] + d2);
  float dist2 = dx*dx + dy*dy + dz*dz;
  if (dist2 < CUT*CUT) {
    int i = atomicAdd(cnt, 1);
    if (i < NMAX) {
      Rec r; r.dx = dx; r.dy = dy; r.dz = dz;
      r.ap = ((unsigned)ag << 16) | (unsigned)pg;
      recs[i] = r;
    }
  }
}

// Fused MLP. Block = 256 threads / 4 waves handles 4 edges per iteration.
// L1: thread = (feature f1 in 0..127, k-half kh in 0..1); each W1 word loaded
// exactly once per block; per-block k-schedule rotated by bt%13 to de-lockstep
// L2 slice demand across blocks. 16-deep ping-pong register buffers.
__global__ __launch_bounds__(256) void mlp_kernel(
    const Rec* __restrict__ recs, const int* __restrict__ cnt,
    const float* __restrict__ S, const float* __restrict__ V,
    const float* __restrict__ W1, const float* __restrict__ b1,
    const float* __restrict__ W2, const float* __restrict__ b2,
    const float* __restrict__ W3, const float* __restrict__ b3,
    float* __restrict__ out) {
  __shared__ float hS[NE][HP];        // 6.8 KB
  __shared__ float h2S[NE][FH + 4];   // 2.1 KB
  __shared__ float part[NE][FH];      // 2.0 KB
  __shared__ float cwS[NE];
  __shared__ unsigned pS[NE];

  const int t    = threadIdx.x;
  const int lane = t & 63;
  const int wave = t >> 6;
  int n = *cnt; if (n > NMAX) n = NMAX;

  const float2* Vf2 = (const float2*)V;
  const float2* Sf2 = (const float2*)S;

  const int f1 = t & 127;     // layer1 output feature
  const int kh = t >> 7;      // k-half: 0 -> k 0..207, 1 -> k 208..415
  const float b1v = b1[f1];
  const float b2v = b2[lane];
  const float w3v = W3[lane];
  const float b3v = b3[0];

  for (int bt = blockIdx.x; bt * NE < n; bt += gridDim.x) {
    // ---------- gather: wave w builds edge w ----------
    {
      const int eg = bt * NE + wave;
      Rec r;
      if (eg < n) r = recs[eg];
      else { r.dx = 1.0f; r.dy = 0.0f; r.dz = 0.0f; r.ap = 0xFFFFFFFFu; }
      unsigned a = (r.ap == 0xFFFFFFFFu) ? 0u : (r.ap >> 16);
      float2 v0 = Vf2[(a*3+0)*64 + lane];
      float2 v1 = Vf2[(a*3+1)*64 + lane];
      float2 v2 = Vf2[(a*3+2)*64 + lane];
      float2 sj = Sf2[a*64 + lane];
      float d = sqrtf(r.dx*r.dx + r.dy*r.dy + r.dz*r.dz);
      float inv = 1.0f / (d + 1e-8f);
      float rh0 = r.dx*inv, rh1 = r.dy*inv, rh2 = r.dz*inv;
      if (lane < DRBF) hS[wave][lane] = sinf(d * (float)(lane+1) * (PI_F/CUT)) / d;
      float2 q;  q.x  = v0.x*rh0 + v1.x*rh1 + v2.x*rh2;
                 q.y  = v0.y*rh0 + v1.y*rh1 + v2.y*rh2;
      float2 nv; nv.x = sqrtf(v0.x*v0.x + v1.x*v1.x + v2.x*v2.x);
                 nv.y = sqrtf(v0.y*v0.y + v1.y*v1.y + v2.y*v2.y);
      *(float2*)&hS[wave][DRBF        + 2*lane] = q;
      *(float2*)&hS[wave][DRBF +   FH + 2*lane] = nv;
      *(float2*)&hS[wave][DRBF + 2*FH + 2*lane] = sj;
      if (lane == 0) {
        cwS[wave] = 0.5f * (cosf((PI_F/CUT) * d) + 1.0f);
        pS[wave]  = (r.ap == 0xFFFFFFFFu) ? 0xFFFFu : (r.ap & 0xFFFFu);
      }
    }
    __syncthreads();

    // ---------- layer 1: 13 groups of 16 k's per k-half, rotated schedule ----------
    {
      const int rot = bt % 13;
      float acc0, acc1, acc2, acc3;
      acc0 = acc1 = acc2 = acc3 = (kh == 0) ? b1v : 0.0f;
      const float* Wb = W1 + f1;
      const int kbase = kh * 208;

      // group g -> k offset
      #define KOF(g_) (kbase + ((((g_) + rot) >= 13) ? ((g_) + rot - 13) : ((g_) + rot)) * 16)
      #define L1G(wbuf, kk)                                                        \
        { _Pragma("unroll")                                                        \
          for (int q = 0; q < 4; ++q) {                                            \
            float4 h0 = *(const float4*)&hS[0][(kk) + q*4];                        \
            float4 h1 = *(const float4*)&hS[1][(kk) + q*4];                        \
            float4 h2_ = *(const float4*)&hS[2][(kk) + q*4];                       \
            float4 h3 = *(const float4*)&hS[3][(kk) + q*4];                        \
            acc0 = fmaf(h0.x, wbuf[q*4+0], acc0); acc1 = fmaf(h1.x, wbuf[q*4+0], acc1); \
            acc2 = fmaf(h2_.x, wbuf[q*4+0], acc2); acc3 = fmaf(h3.x, wbuf[q*4+0], acc3); \
            acc0 = fmaf(h0.y, wbuf[q*4+1], acc0); acc1 = fmaf(h1.y, wbuf[q*4+1], acc1); \
            acc2 = fmaf(h2_.y, wbuf[q*4+1], acc2); acc3 = fmaf(h3.y, wbuf[q*4+1], acc3); \
            acc0 = fmaf(h0.z, wbuf[q*4+2], acc0); acc1 = fmaf(h1.z, wbuf[q*4+2], acc1); \
            acc2 = fmaf(h2_.z, wbuf[q*4+2], acc2); acc3 = fmaf(h3.z, wbuf[q*4+2], acc3); \
            acc0 = fmaf(h0.w, wbuf[q*4+3], acc0); acc1 = fmaf(h1.w, wbuf[q*4+3], acc1); \
            acc2 = fmaf(h2_.w, wbuf[q*4+3], acc2); acc3 = fmaf(h3.w, wbuf[q*4+3], acc3); \
          } }

      float wA[16], wB[16];
      int kA = KOF(0);
      #pragma unroll
      for (int i = 0; i < 16; ++i) wA[i] = Wb[(kA + i)*FH];

      #pragma unroll 1
      for (int p = 0; p < 6; ++p) {
        const int g0 = 2*p;
        int kB = KOF(g0 + 1);
        #pragma unroll
        for (int i = 0; i < 16; ++i) wB[i] = Wb[(kB + i)*FH];
        L1G(wA, kA);
        int kA2 = KOF(g0 + 2);
        #pragma unroll
        for (int i = 0; i < 16; ++i) wA[i] = Wb[(kA2 + i)*FH];
        L1G(wB, kB);
        kA = kA2;
      }
      L1G(wA, kA);   // group 12

      // combine k-halves, apply silu
      if (kh == 1) {
        part[0][f1] = acc0; part[1][f1] = acc1;
        part[2][f1] = acc2; part[3][f1] = acc3;
      }
      __syncthreads();
      if (kh == 0) {
        float z0 = acc0 + part[0][f1];
        float z1 = acc1 + part[1][f1];
        float z2 = acc2 + part[2][f1];
        float z3 = acc3 + part[3][f1];
        h2S[0][f1] = z0 / (1.0f + __expf(-z0));
        h2S[1][f1] = z1 / (1.0f + __expf(-z1));
        h2S[2][f1] = z2 / (1.0f + __expf(-z2));
        h2S[3][f1] = z3 / (1.0f + __expf(-z3));
      }
      #undef KOF
      #undef L1G
    }
    __syncthreads();

    // ---------- layer 2: wave = edge, lane = feature; 8 groups of 16 ----------
    float acc2 = b2v;
    {
      const float* Wp = W2 + lane;
      const float* hp = &h2S[wave][0];
      #define L2G(wbuf, kk)                                        \
        { _Pragma("unroll")                                        \
          for (int q = 0; q < 4; ++q) {                            \
            float4 hv = *(const float4*)(hp + (kk) + q*4);         \
            acc2 = fmaf(hv.x, wbuf[q*4+0], acc2);                  \
            acc2 = fmaf(hv.y, wbuf[q*4+1], acc2);                  \
            acc2 = fmaf(hv.z, wbuf[q*4+2], acc2);                  \
            acc2 = fmaf(hv.w, wbuf[q*4+3], acc2);                  \
          } }
      float wA[16], wB[16];
      #pragma unroll
      for (int i = 0; i < 16; ++i) wA[i] = Wp[i*64];
      #pragma unroll 1
      for (int p = 0; p < 4; ++p) {
        const int kA = p*32, kB = p*32 + 16;
        #pragma unroll
        for (int i = 0; i < 16; ++i) wB[i] = Wp[(kB + i)*64];
        L2G(wA, kA);
        if (p < 3) {
          #pragma unroll
          for (int i = 0; i < 16; ++i) wA[i] = Wp[(kA + 32 + i)*64];
        }
        L2G(wB, kB);
      }
      #undef L2G
    }

    // ---------- layer 3: silu, dot with W3 across 64 lanes, scatter ----------
    {
      float h2 = acc2 / (1.0f + __expf(-acc2));
      float rs = h2 * w3v;
      #pragma unroll
      for (int off = 32; off; off >>= 1) rs += __shfl_xor(rs, off, 64);
      if (lane == 0) {
        unsigned p = pS[wave];
        if (p != 0xFFFFu) atomicAdd(&out[p], (rs + b3v) * cwS[wave]);
      }
    }
    __syncthreads();   // protect hS/h2S before next iteration overwrites
  }
}

extern "C" void kernel_launch(void* const* d_in, const int* in_sizes, int n_in,
                              void* d_out, int out_size, void* d_ws, size_t ws_size,
                              hipStream_t stream) {
  const float* S         = (const float*)d_in[0];
  const float* V         = (const float*)d_in[1];
  const float* atom_xyz  = (const float*)d_in[2];
  const float* probe_xyz = (const float*)d_in[3];
  const float* cell      = (const float*)d_in[4];
  const float* pdisp     = (const float*)d_in[5];
  const float* W1        = (const float*)d_in[6];
  const float* b1        = (const float*)d_in[7];
  const float* W2        = (const float*)d_in[8];
  const float* b2        = (const float*)d_in[9];
  const float* W3        = (const float*)d_in[10];
  const float* b3        = (const float*)d_in[11];
  const int*   pe        = (const int*)d_in[12];
  float* out = (float*)d_out;

  int* cnt  = (int*)d_ws;
  Rec* recs = (Rec*)((char*)d_ws + 256);

  hipMemsetAsync(cnt, 0, 4, stream);
  filter_kernel<<<BB*EE/256, 256, 0, stream>>>(pe, pdisp, cell, atom_xyz, probe_xyz,
                                               cnt, recs, out);
  mlp_kernel<<<384, 256, 0, stream>>>(recs, cnt, S, V, W1, b1, W2, b2, W3, b3, out);
}